// Round 3
// baseline (229.622 us; speedup 1.0000x reference)
//
#include <hip/hip_runtime.h>

#define B_   4
#define S_   2048
#define D_   1024
#define H_   16
#define DKV  64
#define BM   128
#define BN   64
#define NT   (S_ / BN)
#define PITCH 72   // 144 B rows: 16B-aligned, b128 frag reads land evenly on banks

typedef float f32x4 __attribute__((ext_vector_type(4)));
typedef short bf16x8 __attribute__((ext_vector_type(8)));
typedef unsigned int u32x4 __attribute__((ext_vector_type(4)));

__device__ __forceinline__ unsigned short f2b(float f) {      // RNE
  union { float f; unsigned int u; } x; x.f = f;
  unsigned int u = x.u;
  unsigned int r = u + 0x7FFFu + ((u >> 16) & 1u);
  return (unsigned short)(r >> 16);
}
__device__ __forceinline__ unsigned cvtpk(float a, float b) { // (lo=bf16(a), hi=bf16(b)), RNE
  unsigned r;
  asm("v_cvt_pk_bf16_f32 %0, %1, %2" : "=v"(r) : "v"(a), "v"(b));
  return r;
}

// ---------- fully fused: fp32 Q,K,V in; conversion + V-transpose happen at LDS staging ----------
// Two-barrier schedule (round-1 structure, measured faster than 1-barrier dbuf: LDS pipe is
// near-critical, so staging writes must not overlap the MFMA-feeding fragment reads).
// V transpose: cvt_pk(V[n][d],V[n+1][d]) -> one dword at sVt[d][n], key-column XOR-swizzled
// by (d & 0x38) on BOTH write and read sides (8-row stride = 288 dwords = 0 mod 32 banks,
// so unswizzled transposed writes would be 8-way conflicted; swizzled ~2-way = free).
__global__ __launch_bounds__(256, 4)
void mha_fused_kernel(const float* __restrict__ q,
                      const float* __restrict__ k,
                      const float* __restrict__ v,
                      float* __restrict__ out) {
  __shared__ __align__(16) unsigned short sK [BN  * PITCH];
  __shared__ __align__(16) unsigned short sVt[DKV * PITCH];

  const int tid  = threadIdx.x;
  const int wave = tid >> 6;
  const int lane = tid & 63;
  const int ln   = lane & 15;
  const int quad = lane >> 4;

  const int bh = blockIdx.y;
  const int b  = bh >> 4;
  const int h  = bh & 15;
  const int q0 = blockIdx.x * BM;

  const float* qg = q + (size_t)b * S_ * D_ + h * DKV;
  const float* kg = k + (size_t)b * S_ * D_ + h * DKV;
  const float* vg = v + (size_t)b * S_ * D_ + h * DKV;
  float* og = out + (size_t)b * S_ * D_ + h * DKV;

  // staging coordinates
  const int nK = tid >> 2;              // K row (key) 0..63
  const int cK = (tid & 3) << 4;        // K col base (16 shorts per thread)
  const int nV = (tid >> 3) << 1;       // V key pair base 0..62
  const int d8 = (tid & 7) << 3;        // V d base (8 rows per thread)
  const int vcolw = ((nV ^ d8) >> 1);   // swizzled dword column for V writes
  unsigned* sv32 = reinterpret_cast<unsigned*>(sVt);
  const int swzA = ln & 8;              // read-side row-swizzle bit

  // fold 1/sqrt(64)*log2(e) into Q; exp2-domain softmax, no max subtraction
  const float qs = 0.125f * 1.44269504088896340736f;

  // tile-0 loads in flight while we build Q frags
  f32x4 kr0, kr1, kr2, kr3, va0, va1, vb0, vb1;
  {
    const float* kp = kg + (size_t)nK * D_ + cK;
    kr0 = *reinterpret_cast<const f32x4*>(kp);
    kr1 = *reinterpret_cast<const f32x4*>(kp + 4);
    kr2 = *reinterpret_cast<const f32x4*>(kp + 8);
    kr3 = *reinterpret_cast<const f32x4*>(kp + 12);
    const float* vp = vg + (size_t)nV * D_ + d8;
    va0 = *reinterpret_cast<const f32x4*>(vp);
    va1 = *reinterpret_cast<const f32x4*>(vp + 4);
    vb0 = *reinterpret_cast<const f32x4*>(vp + D_);
    vb1 = *reinterpret_cast<const f32x4*>(vp + D_ + 4);
  }

  // Q frags (MFMA *B* operand for S^T): lane holds Q[q=ln][k=quad*8+j]
  bf16x8 qf[2][2];
  for (int mt = 0; mt < 2; ++mt)
    for (int ks = 0; ks < 2; ++ks) {
      const float* base = qg + (size_t)(q0 + wave * 32 + mt * 16 + ln) * D_
                             + ks * 32 + quad * 8;
      const float4 f0 = *reinterpret_cast<const float4*>(base);
      const float4 f1 = *reinterpret_cast<const float4*>(base + 4);
      bf16x8 a;
      a[0] = (short)f2b(f0.x * qs); a[1] = (short)f2b(f0.y * qs);
      a[2] = (short)f2b(f0.z * qs); a[3] = (short)f2b(f0.w * qs);
      a[4] = (short)f2b(f1.x * qs); a[5] = (short)f2b(f1.y * qs);
      a[6] = (short)f2b(f1.z * qs); a[7] = (short)f2b(f1.w * qs);
      qf[mt][ks] = a;
    }

  float l_part[2] = {0.f, 0.f};   // lane ln owns softmax row q=ln (per mt tile)
  f32x4 o[2][4];
  for (int mt = 0; mt < 2; ++mt)
    for (int dt = 0; dt < 4; ++dt) o[mt][dt] = (f32x4){0.f, 0.f, 0.f, 0.f};

  for (int i = 0; i < NT; ++i) {
    __syncthreads();   // all waves done reading previous tile

    // ---- stage tile i from regs: cvt fp32->bf16; V goes in transposed+swizzled ----
    {
      unsigned kw0 = cvtpk(kr0[0], kr0[1]), kw1 = cvtpk(kr0[2], kr0[3]);
      unsigned kw2 = cvtpk(kr1[0], kr1[1]), kw3 = cvtpk(kr1[2], kr1[3]);
      unsigned kw4 = cvtpk(kr2[0], kr2[1]), kw5 = cvtpk(kr2[2], kr2[3]);
      unsigned kw6 = cvtpk(kr3[0], kr3[1]), kw7 = cvtpk(kr3[2], kr3[3]);
      *reinterpret_cast<u32x4*>(&sK[nK * PITCH + cK])     = (u32x4){kw0, kw1, kw2, kw3};
      *reinterpret_cast<u32x4*>(&sK[nK * PITCH + cK + 8]) = (u32x4){kw4, kw5, kw6, kw7};
#pragma unroll
      for (int j = 0; j < 4; ++j)
        sv32[(d8 + j) * (PITCH / 2) + vcolw] = cvtpk(va0[j], vb0[j]);
#pragma unroll
      for (int j = 0; j < 4; ++j)
        sv32[(d8 + 4 + j) * (PITCH / 2) + vcolw] = cvtpk(va1[j], vb1[j]);
    }
    __syncthreads();

    // ---- prefetch tile i+1 into regs (latency hides under the compute below) ----
    if (i + 1 < NT) {
      const int nn = (i + 1) * BN;
      const float* kp = kg + (size_t)(nn + nK) * D_ + cK;
      kr0 = *reinterpret_cast<const f32x4*>(kp);
      kr1 = *reinterpret_cast<const f32x4*>(kp + 4);
      kr2 = *reinterpret_cast<const f32x4*>(kp + 8);
      kr3 = *reinterpret_cast<const f32x4*>(kp + 12);
      const float* vp = vg + (size_t)(nn + nV) * D_ + d8;
      va0 = *reinterpret_cast<const f32x4*>(vp);
      va1 = *reinterpret_cast<const f32x4*>(vp + 4);
      vb0 = *reinterpret_cast<const f32x4*>(vp + D_);
      vb1 = *reinterpret_cast<const f32x4*>(vp + D_ + 4);
    }

    // ---- S^T = K·Q^T per 16-key tile; exp2; pack+redistribute to 16x16x32 A-frags ----
    bf16x8 pA[2][2];   // [mt][g]
    for (int g = 0; g < 2; ++g) {
      unsigned lo[2][2], hi[2][2];   // [mt][t]
      for (int t = 0; t < 2; ++t) {
        const int nt = g * 2 + t;
        bf16x8 kf0 = *reinterpret_cast<const bf16x8*>(&sK[(nt * 16 + ln) * PITCH + quad * 8]);
        bf16x8 kf1 = *reinterpret_cast<const bf16x8*>(&sK[(nt * 16 + ln) * PITCH + 32 + quad * 8]);
        for (int mt = 0; mt < 2; ++mt) {
          f32x4 acc = (f32x4){0.f, 0.f, 0.f, 0.f};
          acc = __builtin_amdgcn_mfma_f32_16x16x32_bf16(kf0, qf[mt][0], acc, 0, 0, 0);
          acc = __builtin_amdgcn_mfma_f32_16x16x32_bf16(kf1, qf[mt][1], acc, 0, 0, 0);
          float p0 = __builtin_amdgcn_exp2f(acc[0]);
          float p1 = __builtin_amdgcn_exp2f(acc[1]);
          float p2 = __builtin_amdgcn_exp2f(acc[2]);
          float p3 = __builtin_amdgcn_exp2f(acc[3]);
          l_part[mt] += (p0 + p1) + (p2 + p3);
          lo[mt][t] = cvtpk(p0, p1);
          hi[mt][t] = cvtpk(p2, p3);
        }
      }
      for (int mt = 0; mt < 2; ++mt) {
        unsigned x = lo[mt][0], y = lo[mt][1];
        asm("v_permlane32_swap_b32 %0, %1" : "+v"(x), "+v"(y));
        asm("v_permlane16_swap_b32 %0, %1" : "+v"(x), "+v"(y));
        unsigned u = hi[mt][0], w = hi[mt][1];
        asm("v_permlane32_swap_b32 %0, %1" : "+v"(u), "+v"(w));
        asm("v_permlane16_swap_b32 %0, %1" : "+v"(u), "+v"(w));
        union { unsigned u32[4]; bf16x8 v8; } pw;
        pw.u32[0] = x; pw.u32[1] = u; pw.u32[2] = y; pw.u32[3] = w;
        pA[mt][g] = pw.v8;
      }
    }

    // ---- O += P·V via full-K 16x16x32 MFMA; V B-frags read with the write-side swizzle ----
    for (int g = 0; g < 2; ++g) {
      for (int dt = 0; dt < 4; ++dt) {
        const int cb = (g * 32 + quad * 8) ^ (dt * 16 + swzA);
        bf16x8 vf = *reinterpret_cast<const bf16x8*>(&sVt[(dt * 16 + ln) * PITCH + cb]);
        for (int mt = 0; mt < 2; ++mt)
          o[mt][dt] = __builtin_amdgcn_mfma_f32_16x16x32_bf16(pA[mt][g], vf, o[mt][dt], 0, 0, 0);
      }
    }
  }

  // ---- epilogue: l lives at lane q=ln; reduce across quads, redistribute, store ----
  for (int mt = 0; mt < 2; ++mt) {
    float l = l_part[mt];
    l += __shfl_xor(l, 16, 64);
    l += __shfl_xor(l, 32, 64);
    const float linv = 1.f / l;               // valid for q = ln (all quads agree)
    float invr[4];
    for (int r = 0; r < 4; ++r)
      invr[r] = __shfl(linv, quad * 4 + r, 64);  // l for row q_local = quad*4+r
    float* orow = og + (size_t)(q0 + wave * 32 + mt * 16 + quad * 4) * D_;
    for (int r = 0; r < 4; ++r)
      for (int dt = 0; dt < 4; ++dt)
        orow[(size_t)r * D_ + dt * 16 + ln] = o[mt][dt][r] * invr[r];
  }
}

extern "C" void kernel_launch(void* const* d_in, const int* in_sizes, int n_in,
                              void* d_out, int out_size, void* d_ws, size_t ws_size,
                              hipStream_t stream) {
  const float* q = (const float*)d_in[0];
  const float* k = (const float*)d_in[1];
  const float* v = (const float*)d_in[2];
  float* out = (float*)d_out;
  (void)d_ws; (void)ws_size;

  mha_fused_kernel<<<dim3(S_ / BM, B_ * H_), dim3(256), 0, stream>>>(q, k, v, out);
}